// Round 1
// baseline (46.356 us; speedup 1.0000x reference)
//
#include <hip/hip_runtime.h>
#include <hip/hip_bf16.h>

using u32 = unsigned int;
using u16 = unsigned short;

typedef __attribute__((ext_vector_type(8))) short short8;
typedef __attribute__((ext_vector_type(16))) float f32x16;

#define IN_K   4096
#define OUT_N  14336
#define NBLK   128      // output columns per block
#define KSPL   512      // K range per block (8-way K split)

// ---- prep: x fp32 -> bf16 into ws; out = bias ----
__global__ __launch_bounds__(256) void prep_kernel(
    const float* __restrict__ x, const float* __restrict__ bias,
    u16* __restrict__ xb, float* __restrict__ out)
{
  const int b = blockIdx.x, t = threadIdx.x;
  if (b < 256) {
    const int idx = (b * 256 + t) * 4;            // 256*256*4 = 262144 = 64*4096
    const float4 v = *(const float4*)(x + idx);
    __hip_bfloat162 h0 = __float22bfloat162_rn(make_float2(v.x, v.y));
    __hip_bfloat162 h1 = __float22bfloat162_rn(make_float2(v.z, v.w));
    u32 lo, hi;
    __builtin_memcpy(&lo, &h0, 4);
    __builtin_memcpy(&hi, &h1, 4);
    uint2 pk; pk.x = lo; pk.y = hi;
    *(uint2*)(xb + idx) = pk;
  } else {
    const int idx = ((b - 256) * 256 + t) * 4;    // 896*1024 = 917504 = 64*14336
    const float4 bv = *(const float4*)(bias + (idx % OUT_N));
    *(float4*)(out + idx) = bv;
  }
}

// dequant one qweight word (8 weights along K) -> bf16x8 B-fragment
// value = s*(w - (z+1)) = fma(float(w), s, c2) with c2 = -s*(z+1)  (exact path)
static __device__ __forceinline__ short8 dequant8(u32 w, float s, float c2) {
  union { short8 v; u32 u[4]; } r;
#pragma unroll
  for (int i = 0; i < 4; ++i) {
    const float f0 = (float)((w >> (8 * i)) & 0xFu);
    const float f1 = (float)((w >> (8 * i + 4)) & 0xFu);
    const float p0 = fmaf(f0, s, c2);
    const float p1 = fmaf(f1, s, c2);
    const __hip_bfloat162 h = __float22bfloat162_rn(make_float2(p0, p1));
    __builtin_memcpy(&r.u[i], &h, 4);
  }
  return r.v;
}

__global__ __launch_bounds__(256) void qgemm_kernel(
    const u32* __restrict__ qw, const u32* __restrict__ qz,
    const float* __restrict__ sc, const u16* __restrict__ xb,
    float* __restrict__ out)
{
  // x tile staging: [64 rows][128 k] bf16 per stage, double-buffered (32 KB)
  __shared__ u16 lds[2][64 * 128];
  const int tid  = threadIdx.x;
  const int lane = tid & 63;
  const int wv   = tid >> 6;       // wave id 0..3 -> 32-col slice
  const int g    = lane >> 5;      // k-group half within fragment
  const int nn   = lane & 31;      // row (A) / col (B,C) within 32
  const int colabs = blockIdx.x * NBLK + wv * 32 + nn;
  const int kbase  = blockIdx.y * KSPL;

  f32x16 acc0, acc1;
#pragma unroll
  for (int i = 0; i < 16; ++i) { acc0[i] = 0.f; acc1[i] = 0.f; }

  // stage issue: 64x128 bf16 = 1024 chunks of 16B; 256 thr x 4 rounds.
  // LDS dest linear (required by global_load_lds); source k-chunk XOR-swizzled.
  auto issue = [&](int st) {
    const int kpos = kbase + st * 128;
    u16* dst = &lds[st & 1][0];
#pragma unroll
    for (int r = 0; r < 4; ++r) {
      const int p  = r * 256 + tid;
      const int m  = p >> 4;          // row 0..63
      const int sl = p & 15;          // 16B slot within row
      const int c  = sl ^ (m & 15);   // source chunk (involution)
      const u16* src = xb + m * IN_K + kpos + c * 8;
      __builtin_amdgcn_global_load_lds(
          (const __attribute__((address_space(1))) void*)src,
          (__attribute__((address_space(3))) void*)(dst + p * 8),
          16, 0, 0);
    }
  };

  issue(0);
#pragma unroll 1
  for (int st = 0; st < 4; ++st) {
    if (st) __syncthreads();              // all waves done computing stage st-1
    if (st < 3) {
      issue(st + 1);                      // prefetch next stage (other buffer)
      asm volatile("s_waitcnt vmcnt(4)" ::: "memory");  // stage st loads done
    } else {
      asm volatile("s_waitcnt vmcnt(0)" ::: "memory");
    }
    __builtin_amdgcn_s_barrier();         // cross-wave: all stage-st LDS writes visible
    asm volatile("" ::: "memory");

    // per-group (KTILE==GROUP==128) dequant constants for this lane's column
    const int grp = (kbase >> 7) + st;
    const float s = sc[grp * OUT_N + colabs];
    const u32  zw = qz[grp * (OUT_N / 8) + (colabs >> 3)];
    const float zf = (float)(((zw >> ((colabs & 7) * 4)) & 0xFu) + 1u);
    const float c2 = -s * zf;
    const u16* buf = &lds[st & 1][0];
    const int qrow0 = (kbase >> 3) + st * 16 + g;

#pragma unroll
    for (int t16 = 0; t16 < 8; ++t16) {
      // B fragment: one packed word per lane = weights k0+8g+0..7 of column colabs
      const u32 w = qw[(qrow0 + 2 * t16) * OUT_N + colabs];
      // A fragments: rows nn and nn+32, k-chunk 2*t16+g (swizzled slot)
      const int ch = 2 * t16 + g;
      const int sl = (ch ^ (nn & 15)) * 8;
      const short8 a0 = *(const short8*)(buf + nn * 128 + sl);
      const short8 a1 = *(const short8*)(buf + (nn + 32) * 128 + sl);
      const short8 bb = dequant8(w, s, c2);
      acc0 = __builtin_amdgcn_mfma_f32_32x32x16_bf16(a0, bb, acc0, 0, 0, 0);
      acc1 = __builtin_amdgcn_mfma_f32_32x32x16_bf16(a1, bb, acc1, 0, 0, 0);
    }
  }

  // C/D layout (verified m74/m101): col = lane&31, row = (reg&3)+8*(reg>>2)+4*(lane>>5)
#pragma unroll
  for (int r = 0; r < 16; ++r) {
    const int row = (r & 3) + 8 * (r >> 2) + 4 * g;
    unsafeAtomicAdd(&out[row * OUT_N + colabs], acc0[r]);
    unsafeAtomicAdd(&out[(row + 32) * OUT_N + colabs], acc1[r]);
  }
}

extern "C" void kernel_launch(void* const* d_in, const int* in_sizes, int n_in,
                              void* d_out, int out_size, void* d_ws, size_t ws_size,
                              hipStream_t stream) {
  (void)in_sizes; (void)n_in; (void)out_size; (void)ws_size;
  const float* x    = (const float*)d_in[0];
  const u32*   qw   = (const u32*)d_in[1];
  const u32*   qz   = (const u32*)d_in[2];
  const float* sc   = (const float*)d_in[3];
  const float* bias = (const float*)d_in[4];
  // d_in[5] = g_idx: sequential (k/128) for this problem; folded into indexing.
  float* out = (float*)d_out;
  u16*   xb  = (u16*)d_ws;   // 64*4096 bf16 = 512 KB scratch

  prep_kernel<<<1152, 256, 0, stream>>>(x, bias, xb, out);
  qgemm_kernel<<<dim3(112, 8), 256, 0, stream>>>(qw, qz, sc, xb, out);
}

// Round 2
// 29.675 us; speedup vs baseline: 1.5621x; 1.5621x over previous
//
#include <hip/hip_runtime.h>
#include <hip/hip_bf16.h>

using u32 = unsigned int;
using u16 = unsigned short;

typedef __attribute__((ext_vector_type(8))) _Float16 half8;
typedef __attribute__((ext_vector_type(2))) _Float16 half2v;
typedef __attribute__((ext_vector_type(16))) float f32x16;
typedef __attribute__((ext_vector_type(4))) u32 u32x4;

#define IN_K   4096
#define OUT_N  14336
#define SPLITK 4
#define NSTAGE 8          // stages of 128 k per block (K_block = 1024)
#define OUT_ELEMS (64 * OUT_N)   // 917504

// ---------------------------------------------------------------------------
// prep: x f32[64][4096] -> xs f16 in MFMA-fragment order.
// xs layout: [512 chunks][64 rows][8 f16]; chunk c covers k = 8c + perm[j],
// perm = {0,4,1,5,2,6,3,7} (matches the pair-dequant element order).
__global__ __launch_bounds__(256) void prep_kernel(const float* __restrict__ x,
                                                   u16* __restrict__ xs) {
  const int t = blockIdx.x * 256 + threadIdx.x;   // 32768 threads
  const int c = t >> 6;        // chunk 0..511
  const int r = t & 63;        // row
  const float* px = x + r * IN_K + c * 8;
  const float4 a = *(const float4*)px;
  const float4 b = *(const float4*)(px + 4);
  const float af[4] = {a.x, a.y, a.z, a.w};
  const float bf[4] = {b.x, b.y, b.z, b.w};
  union { u32x4 v; u32 u[4]; } o;
#pragma unroll
  for (int i = 0; i < 4; ++i) {
    const _Float16 hl = (_Float16)af[i];   // k = 8c + i
    const _Float16 hh = (_Float16)bf[i];   // k = 8c + i + 4
    u16 lo, hi;
    __builtin_memcpy(&lo, &hl, 2);
    __builtin_memcpy(&hi, &hh, 2);
    o.u[i] = (u32)lo | ((u32)hi << 16);
  }
  *(u32x4*)(xs + (size_t)t * 8) = o.v;
}

// ---------------------------------------------------------------------------
__global__ __launch_bounds__(256) void bias_init_kernel(const float* __restrict__ bias,
                                                        float* __restrict__ out) {
  const int i = (blockIdx.x * 256 + threadIdx.x) * 4;
  const int col = i % OUT_N;
  *(float4*)(out + i) = *(const float4*)(bias + col);
}

__global__ __launch_bounds__(256) void reduce_kernel(const float* __restrict__ part,
                                                     const float* __restrict__ bias,
                                                     float* __restrict__ out) {
  const int i = (blockIdx.x * 256 + threadIdx.x) * 4;
  const int col = i % OUT_N;
  const float4 a0 = *(const float4*)(part + i);
  const float4 a1 = *(const float4*)(part + (size_t)OUT_ELEMS + i);
  const float4 a2 = *(const float4*)(part + 2 * (size_t)OUT_ELEMS + i);
  const float4 a3 = *(const float4*)(part + 3 * (size_t)OUT_ELEMS + i);
  const float4 bv = *(const float4*)(bias + col);
  float4 r;
  r.x = a0.x + a1.x + a2.x + a3.x + bv.x;
  r.y = a0.y + a1.y + a2.y + a3.y + bv.y;
  r.z = a0.z + a1.z + a2.z + a3.z + bv.z;
  r.w = a0.w + a1.w + a2.w + a3.w + bv.w;
  *(float4*)(out + i) = r;
}

// ---------------------------------------------------------------------------
// qgemm: grid (112, 4). Block: 4 waves, each a 32-col slice x 64 rows,
// K_block = 1024 (8 stages of 128 k). A staged via global_load_lds (linear,
// already fragment-ordered), weights dequanted in-register to f16 pairs.
template <bool ATOMIC>
__global__ __launch_bounds__(256, 2) void qgemm_kernel(
    const u32* __restrict__ qw, const u32* __restrict__ qz,
    const float* __restrict__ scal, const u16* __restrict__ xs,
    float* __restrict__ dst) {
  __shared__ u16 lds[2][8192];             // 2 x 16 KB stages
  const int tid = threadIdx.x;
  const int lane = tid & 63;
  const int wv = tid >> 6;
  const int g = lane >> 5;                 // k-half within 16k step
  const int nn = lane & 31;
  const int colabs = blockIdx.x * 128 + wv * 32 + nn;
  const int by = blockIdx.y;
  const int chunk0 = by * 128;             // global 8k-chunk base (== qw row base)

  f32x16 acc0, acc1;
#pragma unroll
  for (int i = 0; i < 16; ++i) { acc0[i] = 0.f; acc1[i] = 0.f; }

  auto issue = [&](int st) {
    const u16* src = xs + (size_t)(chunk0 + st * 16) * 512;   // 16 KB contiguous
    u16* dstl = &lds[st & 1][0];
#pragma unroll
    for (int r = 0; r < 4; ++r) {
      const int p = r * 256 + tid;
      __builtin_amdgcn_global_load_lds(
          (const __attribute__((address_space(1))) void*)(src + p * 8),
          (__attribute__((address_space(3))) void*)(dstl + p * 8), 16, 0, 0);
    }
  };

  issue(0);
  // stage-0 operand prefetch
  u32 qn[8];
#pragma unroll
  for (int s = 0; s < 8; ++s)
    qn[s] = qw[(size_t)(chunk0 + 2 * s + g) * OUT_N + colabs];
  float sn = scal[(size_t)(by * 8) * OUT_N + colabs];
  u32 zn = qz[(size_t)(by * 8) * (OUT_N / 8) + (colabs >> 3)];

#pragma unroll
  for (int st = 0; st < NSTAGE; ++st) {
    u32 qc[8];
#pragma unroll
    for (int s = 0; s < 8; ++s) qc[s] = qn[s];
    const float scur = sn;
    const u32 zcur = zn;

    if (st < NSTAGE - 1) {
      __builtin_amdgcn_s_barrier();                    // buf (st+1)&1 free to overwrite
      asm volatile("" ::: "memory");
      issue(st + 1);
      asm volatile("s_waitcnt vmcnt(4)" ::: "memory"); // stage st gl_lds complete
    } else {
      asm volatile("s_waitcnt vmcnt(0)" ::: "memory");
    }
    __builtin_amdgcn_s_barrier();                      // stage st visible to all waves
    asm volatile("" ::: "memory");

    if (st < NSTAGE - 1) {                             // prefetch next stage operands
      const int c1 = chunk0 + (st + 1) * 16;
#pragma unroll
      for (int s = 0; s < 8; ++s)
        qn[s] = qw[(size_t)(c1 + 2 * s + g) * OUT_N + colabs];
      sn = scal[(size_t)(by * 8 + st + 1) * OUT_N + colabs];
      zn = qz[(size_t)(by * 8 + st + 1) * (OUT_N / 8) + (colabs >> 3)];
    }

    // per-stage (== per-group, GROUP=128) dequant constants
    const u32 zq = (zcur >> ((colabs & 7) * 4)) & 0xFu;
    const u32 hzu = 0x64016401u + zq * 0x00010001u;    // f16x2 of (1025+z)
    half2v hz; __builtin_memcpy(&hz, &hzu, 4);
    const _Float16 hs = (_Float16)scur;
    const half2v s2 = {hs, hs};

    const u16* buf = &lds[st & 1][0];
#pragma unroll
    for (int s = 0; s < 8; ++s) {
      const int cl = s * 2 + g;
      const half8 a0 = *(const half8*)(buf + (cl * 64 + nn) * 8);
      const half8 a1 = *(const half8*)(buf + (cl * 64 + nn + 32) * 8);
      const u32 q = qc[s];
      const u32 p0 = (q & 0x000F000Fu) | 0x64006400u;          // (n0,n4)+1024
      const u32 p1 = ((q >> 4) & 0x000F000Fu) | 0x64006400u;   // (n1,n5)+1024
      const u32 p2 = ((q >> 8) & 0x000F000Fu) | 0x64006400u;   // (n2,n6)+1024
      const u32 p3 = ((q >> 12) & 0x000F000Fu) | 0x64006400u;  // (n3,n7)+1024
      half2v t0, t1, t2, t3;
      __builtin_memcpy(&t0, &p0, 4);
      __builtin_memcpy(&t1, &p1, 4);
      __builtin_memcpy(&t2, &p2, 4);
      __builtin_memcpy(&t3, &p3, 4);
      union { half8 v; half2v h[4]; } bb;
      bb.h[0] = (t0 - hz) * s2;    // exact int sub, then scale (v_pk_*_f16)
      bb.h[1] = (t1 - hz) * s2;
      bb.h[2] = (t2 - hz) * s2;
      bb.h[3] = (t3 - hz) * s2;
      acc0 = __builtin_amdgcn_mfma_f32_32x32x16_f16(a0, bb.v, acc0, 0, 0, 0);
      acc1 = __builtin_amdgcn_mfma_f32_32x32x16_f16(a1, bb.v, acc1, 0, 0, 0);
    }
  }

  // C/D layout: col = lane&31, row = (r&3) + 8*(r>>2) + 4*(lane>>5)
#pragma unroll
  for (int r = 0; r < 16; ++r) {
    const int row = (r & 3) + 8 * (r >> 2) + 4 * g;
    if (ATOMIC) {
      unsafeAtomicAdd(&dst[(size_t)row * OUT_N + colabs], acc0[r]);
      unsafeAtomicAdd(&dst[(size_t)(row + 32) * OUT_N + colabs], acc1[r]);
    } else {
      float* p = dst + (size_t)by * OUT_ELEMS;
      p[(size_t)row * OUT_N + colabs] = acc0[r];
      p[(size_t)(row + 32) * OUT_N + colabs] = acc1[r];
    }
  }
}

// ---------------------------------------------------------------------------
extern "C" void kernel_launch(void* const* d_in, const int* in_sizes, int n_in,
                              void* d_out, int out_size, void* d_ws, size_t ws_size,
                              hipStream_t stream) {
  (void)in_sizes; (void)n_in; (void)out_size;
  const float* x    = (const float*)d_in[0];
  const u32*   qw   = (const u32*)d_in[1];
  const u32*   qz   = (const u32*)d_in[2];
  const float* sc   = (const float*)d_in[3];
  const float* bias = (const float*)d_in[4];
  // d_in[5] = g_idx: sequential k/128 for this problem; folded into indexing.
  float* out = (float*)d_out;

  const size_t XS_BYTES   = (size_t)64 * IN_K * 2;              // 512 KB
  const size_t PART_BYTES = (size_t)SPLITK * OUT_ELEMS * 4;     // 14.68 MB
  u16* xs = (u16*)d_ws;

  prep_kernel<<<128, 256, 0, stream>>>(x, xs);

  if (ws_size >= XS_BYTES + PART_BYTES) {
    float* part = (float*)((char*)d_ws + XS_BYTES);
    qgemm_kernel<false><<<dim3(112, SPLITK), 256, 0, stream>>>(qw, qz, sc, xs, part);
    reduce_kernel<<<896, 256, 0, stream>>>(part, bias, out);
  } else {
    bias_init_kernel<<<896, 256, 0, stream>>>(bias, out);
    qgemm_kernel<true><<<dim3(112, SPLITK), 256, 0, stream>>>(qw, qz, sc, xs, out);
  }
}